// Round 7
// baseline (468.312 us; speedup 1.0000x reference)
//
#include <hip/hip_runtime.h>
#include <math.h>

typedef __bf16 bf16_t;
typedef __bf16 bf16x8 __attribute__((ext_vector_type(8)));
typedef float f32x4 __attribute__((ext_vector_type(4)));

#define NN 8192
#define L2E 1.44269504088896340736f
#define SMAX 45.0f                    // fixed softmax max: s in [-75,+15] after shift, all normal fp32/bf16
#define KSCALE 0.35355339059327373f   // 1/sqrt(8); applied to khs on both sides => kh·kh/8

// ---------------------------------------------------------------------------
// Kernel P1: input/weight conversion only (fast, ~6 us).
//  blocks [0,2048)    : input f32 [8192][512] -> inputH/inputL bf16 hi/lo
//  blocks [2048,2080) : kW,vW -> wimgH/wimgL in B-fragment order
// ---------------------------------------------------------------------------
__global__ __launch_bounds__(256) void prep1_kernel(
    const float* __restrict__ input,
    const float* __restrict__ kW,
    const float* __restrict__ vW,
    bf16_t* __restrict__ inputH,
    bf16_t* __restrict__ inputL,
    bf16_t* __restrict__ wimgH,
    bf16_t* __restrict__ wimgL)
{
    const int b = blockIdx.x;
    if (b < 2048) {
        const size_t idx = ((size_t)b * 256 + threadIdx.x) * 8;
        f32x4 a0 = *(const f32x4*)&input[idx];
        f32x4 a1 = *(const f32x4*)&input[idx + 4];
        bf16x8 h8, l8;
        #pragma unroll
        for (int j = 0; j < 4; ++j) {
            bf16_t h0 = (bf16_t)a0[j], h1 = (bf16_t)a1[j];
            h8[j]     = h0;  l8[j]     = (bf16_t)(a0[j] - (float)h0);
            h8[4 + j] = h1;  l8[4 + j] = (bf16_t)(a1[j] - (float)h1);
        }
        *(bf16x8*)&inputH[idx] = h8;
        *(bf16x8*)&inputL[idx] = l8;
    } else {
        const int gid  = (b - 2048) * 256 + threadIdx.x;   // [0, 8192)
        const int proj = gid >> 12;
        const int r    = gid & 4095;
        const int frag = r >> 6;            // kc*4 + nb
        const int lane = r & 63;
        const int kc   = frag >> 2;
        const int nb   = frag & 3;
        const int quad = lane >> 4;
        const int l15  = lane & 15;
        const float* W = proj ? vW : kW;
        bf16x8 h8, l8;
        #pragma unroll
        for (int j = 0; j < 8; ++j) {
            float w  = W[(size_t)(kc * 32 + quad * 8 + j) * 64 + nb * 16 + l15];
            bf16_t h = (bf16_t)w;
            h8[j] = h;
            l8[j] = (bf16_t)(w - (float)h);
        }
        ((bf16x8*)wimgH)[gid] = h8;
        ((bf16x8*)wimgL)[gid] = l8;
    }
}

// ---------------------------------------------------------------------------
// Kernel P2: proj + pack fused for CONCURRENCY. proj (blocks [0,512)) is
// L2/MFMA-bound with idle HBM; pack (blocks [512,1536)) is pure HBM stream
// with idle compute. Co-resident blocks overlap the two -> combined time ~=
// max(pack, proj) instead of sum.
//   proj: wave w: proj=w>>2 (0=K,1=V), nb=w&3; B-fragments from the weight
//   image (verified R2/R5 math). Emits row-major khs_hi/lo (Q fragments) and
//   K/V MFMA-fragment images khsF/vhF (attn 1KB-burst operands, R5-verified).
//   pack: adj (268 MB) -> bitmask [8192][256] u32; sequential grid-stride.
// ---------------------------------------------------------------------------
__global__ __launch_bounds__(512) void projpack_kernel(
    const bf16_t* __restrict__ inputH,
    const bf16_t* __restrict__ inputL,
    const bf16_t* __restrict__ wimgH,
    const bf16_t* __restrict__ wimgL,
    const int*    __restrict__ adj,
    bf16_t* __restrict__ khs_hi,
    bf16_t* __restrict__ khs_lo,
    bf16_t* __restrict__ khsF,
    bf16_t* __restrict__ vhF,
    unsigned int* __restrict__ bits)
{
    const int tid   = threadIdx.x;
    const int lane  = tid & 63;

    if (blockIdx.x >= 512) {
        // ---- pack role: 1024 blocks x 8 waves, 32 chunks/wave ----
        const int gw = (blockIdx.x - 512) * 8 + (tid >> 6);
        const int nw = 1024 * 8;
        const int nchunks = (NN / 256) * NN;          // 262144 chunks of 256 ints
        for (int c = gw; c < nchunks; c += nw) {
            const int* p = adj + (size_t)c * 256;
            unsigned int* o = bits + (size_t)c * 8;
            #pragma unroll
            for (int k = 0; k < 4; ++k) {
                int v = p[k * 64 + lane];             // coalesced 256B per instr
                unsigned long long m = __ballot(v > 0);
                if (lane == 0) *(uint2*)(o + 2 * k) = *(uint2*)&m;   // 8B store
            }
        }
        return;
    }

    // ---- proj role (identical math to R5) ----
    const int w     = tid >> 6;
    const int proj  = w >> 2;
    const int nb    = w & 3;
    const int l15   = lane & 15;
    const int quad  = lane >> 4;
    const int rbase = blockIdx.x * 16;

    const bf16x8* ah_p = (const bf16x8*)&inputH[(size_t)(rbase + l15) * 512 + quad * 8];
    const bf16x8* al_p = (const bf16x8*)&inputL[(size_t)(rbase + l15) * 512 + quad * 8];
    const bf16x8* bh_p = (const bf16x8*)wimgH + ((size_t)proj * 64 + nb) * 64 + lane;
    const bf16x8* bl_p = (const bf16x8*)wimgL + ((size_t)proj * 64 + nb) * 64 + lane;

    f32x4 acc = {};
    #pragma unroll
    for (int kc = 0; kc < 16; ++kc) {
        bf16x8 ah = ah_p[kc * 4];
        bf16x8 al = al_p[kc * 4];
        bf16x8 bh = bh_p[(size_t)kc * 256];
        bf16x8 bl = bl_p[(size_t)kc * 256];
        acc = __builtin_amdgcn_mfma_f32_16x16x32_bf16(ah, bh, acc, 0, 0, 0);
        acc = __builtin_amdgcn_mfma_f32_16x16x32_bf16(al, bh, acc, 0, 0, 0);
        acc = __builtin_amdgcn_mfma_f32_16x16x32_bf16(ah, bl, acc, 0, 0, 0);
    }

    const int dcol = nb * 16 + l15;
    if (proj == 0) {
        // K: row-major hi/lo (Q fragments) + fragment image (attn B-operand, hi)
        const int kcF = nb >> 1;                                   // k>>5
        const int lf  = (quad * 4) + ((((nb << 1) + (l15 >> 3)) & 3) << 4);
        const int jF  = l15 & 7;                                   // k&7
        bf16_t* kf = &khsF[((size_t)(blockIdx.x * 2 + kcF) * 64 + lf) * 8 + jF];
        #pragma unroll
        for (int r = 0; r < 4; ++r) {
            float v  = acc[r] * KSCALE;
            bf16_t h = (bf16_t)v;
            khs_hi[(size_t)(rbase + quad * 4 + r) * 64 + dcol] = h;
            khs_lo[(size_t)(rbase + quad * 4 + r) * 64 + dcol] = (bf16_t)(v - (float)h);
            kf[r * 8] = h;                      // lane_f advances 1 per key => +8 elems
        }
    } else {
        // V: fragment image only. j = key&7 = (quad&1)*4 + r -> one uint2 store.
        const int kt = blockIdx.x >> 1;                            // key>>5
        const int lf = l15 + ((((blockIdx.x << 1) + (quad >> 1)) & 3) << 4);
        union { bf16_t b[4]; uint2 u; } pk;
        #pragma unroll
        for (int r = 0; r < 4; ++r) pk.b[r] = (bf16_t)acc[r];
        *(uint2*)&vhF[((size_t)(kt * 4 + nb) * 64 + lf) * 8 + (quad & 1) * 4] = pk.u;
    }
}

// ---------------------------------------------------------------------------
// Kernel 2: fixed-max flash attention, swapped-QK^T / in-register P-transpose.
// grid 512 row-blocks x 512 threads (8 waves); wave w owns 1024 cols (32x32).
// K/V stream from fragment images (1KB contiguous bursts, R5-verified).
// One-level K prefetch: t+1's K fragments load right after the S-MFMAs
// consume t's — hides the exposed L2 latency (pipe-sum 54us vs observed 70).
// +16 VGPR (est ~124, under the (512,4) cap of 128; WRITE_SIZE = spill trap).
// ---------------------------------------------------------------------------
__global__ __launch_bounds__(512, 4) void attn_kernel(
    const unsigned int* __restrict__ bits,  // [8192][256]
    const bf16_t* __restrict__ khs_hi,
    const bf16_t* __restrict__ khs_lo,
    const bf16_t* __restrict__ khsF,        // fragment image, hi
    const bf16_t* __restrict__ vhF,         // fragment image
    float* __restrict__ out)                // [8192][64]
{
    __shared__ __align__(16) float M[4 * 16 * 68];   // merge buffer only (17.4 KB)

    const int tid   = threadIdx.x;
    const int w     = tid >> 6;
    const int lane  = tid & 63;
    const int l15   = lane & 15;
    const int quad  = lane >> 4;
    const int qbase = blockIdx.x * 16;
    const int colstart = w * 1024;

    // Q fragments (m=l15, k=quad*8+j), hi + lo — used as B-operand (n=l15).
    const bf16x8 qh0 = *(const bf16x8*)&khs_hi[(size_t)(qbase + l15) * 64 + quad * 8];
    const bf16x8 qh1 = *(const bf16x8*)&khs_hi[(size_t)(qbase + l15) * 64 + 32 + quad * 8];
    const bf16x8 ql0 = *(const bf16x8*)&khs_lo[(size_t)(qbase + l15) * 64 + quad * 8];
    const bf16x8 ql1 = *(const bf16x8*)&khs_lo[(size_t)(qbase + l15) * 64 + 32 + quad * 8];

    bf16x8 ones;
    #pragma unroll
    for (int j = 0; j < 8; ++j) ones[j] = (bf16_t)1.0f;

    f32x4 o0 = {}, o1 = {}, o2 = {}, o3 = {}, o4 = {};

    // each lane tracks its own query row's mask words
    const unsigned int* bpl = bits + (size_t)(qbase + l15) * 256 + (colstart >> 5);
    unsigned int mcur = bpl[0], mnxt;

    // fragment streams: contiguous, +256 bf16x8 (4KB) per iter
    const bf16x8* kF = (const bf16x8*)khsF + (size_t)(colstart >> 4) * 128 + lane;
    const bf16x8* vF = (const bf16x8*)vhF  + (size_t)(colstart >> 5) * 256 + lane;

    // bpermute source lanes for the in-register P transpose:
    // target (l15, q) takes keys 8q..8q+7 from source quads (2q)&3 and (2q|1)&3.
    const int idxA = (l15 + (((2 * quad)    ) & 3) * 16) * 4;
    const int idxB = (l15 + (((2 * quad) | 1) & 3) * 16) * 4;

    // K prefetch: t=0 fragments loaded before the loop
    bf16x8 bh00 = kF[0];
    bf16x8 bh01 = kF[64];
    bf16x8 bh10 = kF[128];
    bf16x8 bh11 = kF[192];

    for (int t = 0; t < 32; ++t) {
        // V loads for current iter (consumed after exp/transpose — hidden)
        bf16x8 bv0 = vF[t * 256];
        bf16x8 bv1 = vF[t * 256 + 64];
        bf16x8 bv2 = vF[t * 256 + 128];
        bf16x8 bv3 = vF[t * 256 + 192];

        // mask-word prefetch for t+1 (wraps at t=31, discarded)
        mnxt = bpl[(t + 1) & 31];

        // S^T: query = lane&15 (col), key = quad*4+reg (row). Swapped operands,
        // bitwise-identical dot products to the Q-major form.
        f32x4 zz = {};
        f32x4 s0 = __builtin_amdgcn_mfma_f32_16x16x32_bf16(bh00, qh0, zz, 0, 0, 0);
        s0 = __builtin_amdgcn_mfma_f32_16x16x32_bf16(bh01, qh1, s0, 0, 0, 0);
        s0 = __builtin_amdgcn_mfma_f32_16x16x32_bf16(bh00, ql0, s0, 0, 0, 0);
        s0 = __builtin_amdgcn_mfma_f32_16x16x32_bf16(bh01, ql1, s0, 0, 0, 0);
        f32x4 s1 = __builtin_amdgcn_mfma_f32_16x16x32_bf16(bh10, qh0, zz, 0, 0, 0);
        s1 = __builtin_amdgcn_mfma_f32_16x16x32_bf16(bh11, qh1, s1, 0, 0, 0);
        s1 = __builtin_amdgcn_mfma_f32_16x16x32_bf16(bh10, ql0, s1, 0, 0, 0);
        s1 = __builtin_amdgcn_mfma_f32_16x16x32_bf16(bh11, ql1, s1, 0, 0, 0);

        // K prefetch for t+1 (issued after S-MFMAs consumed bh*; latency hides
        // under exp/transpose/PV; wraps at t=31, result discarded)
        const int tn = (t + 1) & 31;
        bf16x8 nh00 = kF[tn * 256];
        bf16x8 nh01 = kF[tn * 256 + 64];
        bf16x8 nh10 = kF[tn * 256 + 128];
        bf16x8 nh11 = kF[tn * 256 + 192];

        // p = maskbit ? exp(s - SMAX) : 0; key for s0[r] = colbase+quad*4+r,
        // for s1[r] = colbase+16+quad*4+r; mask row = qbase+l15 (own row!)
        union { bf16_t b[2]; int u; } k0, k1, k2, k3;
        #pragma unroll
        for (int r = 0; r < 4; ++r) {
            float p0 = ((mcur >> (quad * 4 + r)) & 1u)
                         ? __builtin_amdgcn_exp2f((s0[r] - SMAX) * L2E) : 0.f;
            float p1 = ((mcur >> (16 + quad * 4 + r)) & 1u)
                         ? __builtin_amdgcn_exp2f((s1[r] - SMAX) * L2E) : 0.f;
            if (r < 2) { k0.b[r] = (bf16_t)p0; k2.b[r] = (bf16_t)p1; }
            else       { k1.b[r - 2] = (bf16_t)p0; k3.b[r - 2] = (bf16_t)p1; }
        }

        // in-register transpose: pull bf16 pairs from the source quads
        int a0 = __builtin_amdgcn_ds_bpermute(idxA, k0.u);
        int a1 = __builtin_amdgcn_ds_bpermute(idxA, k1.u);
        int a2 = __builtin_amdgcn_ds_bpermute(idxB, k0.u);
        int a3 = __builtin_amdgcn_ds_bpermute(idxB, k1.u);
        int c0 = __builtin_amdgcn_ds_bpermute(idxA, k2.u);
        int c1 = __builtin_amdgcn_ds_bpermute(idxA, k3.u);
        int c2 = __builtin_amdgcn_ds_bpermute(idxB, k2.u);
        int c3 = __builtin_amdgcn_ds_bpermute(idxB, k3.u);

        union { int u[4]; bf16x8 v; } pa;
        pa.u[0] = quad < 2 ? a0 : c0;
        pa.u[1] = quad < 2 ? a1 : c1;
        pa.u[2] = quad < 2 ? a2 : c2;
        pa.u[3] = quad < 2 ? a3 : c3;

        // unnormalized accumulation: O += P·V, l += P·1  (no rescale — fixed max)
        o0 = __builtin_amdgcn_mfma_f32_16x16x32_bf16(pa.v, bv0, o0, 0, 0, 0);
        o1 = __builtin_amdgcn_mfma_f32_16x16x32_bf16(pa.v, bv1, o1, 0, 0, 0);
        o2 = __builtin_amdgcn_mfma_f32_16x16x32_bf16(pa.v, bv2, o2, 0, 0, 0);
        o3 = __builtin_amdgcn_mfma_f32_16x16x32_bf16(pa.v, bv3, o3, 0, 0, 0);
        o4 = __builtin_amdgcn_mfma_f32_16x16x32_bf16(pa.v, ones, o4, 0, 0, 0);

        bh00 = nh00; bh01 = nh01; bh10 = nh10; bh11 = nh11;
        mcur = mnxt;
    }

    // ---- sum-tree merge of the 8 waves (pure adds) ----
    #pragma unroll
    for (int s = 4; s >= 1; s >>= 1) {
        __syncthreads();
        if (w >= s && w < 2 * s) {
            float* base = M + (w - s) * 16 * 68;
            #pragma unroll
            for (int r = 0; r < 4; ++r) {
                const int row = quad * 4 + r;
                base[row * 68 + l15]      = o0[r];
                base[row * 68 + 16 + l15] = o1[r];
                base[row * 68 + 32 + l15] = o2[r];
                base[row * 68 + 48 + l15] = o3[r];
                if (l15 == 0) base[row * 68 + 64] = o4[r];
            }
        }
        __syncthreads();
        if (w < s) {
            float* base = M + w * 16 * 68;
            #pragma unroll
            for (int r = 0; r < 4; ++r) {
                const int row = quad * 4 + r;
                o0[r] += base[row * 68 + l15];
                o1[r] += base[row * 68 + 16 + l15];
                o2[r] += base[row * 68 + 32 + l15];
                o3[r] += base[row * 68 + 48 + l15];
                o4[r] += base[row * 68 + 64];   // all 16 lanes same value invariant
            }
        }
    }

    // ---- fused normalize + ELU + store (block owns the whole row) ----
    if (w == 0) {
        #pragma unroll
        for (int r = 0; r < 4; ++r) {
            const size_t row = (size_t)qbase + quad * 4 + r;
            float l   = o4[r];
            float inv = 1.0f / (l > 0.f ? l : 1.0f);
            float v0 = o0[r] * inv, v1 = o1[r] * inv, v2 = o2[r] * inv, v3 = o3[r] * inv;
            out[row * 64 + l15]      = v0 > 0.f ? v0 : expm1f(v0);
            out[row * 64 + 16 + l15] = v1 > 0.f ? v1 : expm1f(v1);
            out[row * 64 + 32 + l15] = v2 > 0.f ? v2 : expm1f(v2);
            out[row * 64 + 48 + l15] = v3 > 0.f ? v3 : expm1f(v3);
        }
    }
}

// ---------------------------------------------------------------------------
extern "C" void kernel_launch(void* const* d_in, const int* in_sizes, int n_in,
                              void* d_out, int out_size, void* d_ws, size_t ws_size,
                              hipStream_t stream) {
    const float* input = nullptr;
    const int*   adj   = nullptr;
    const float* kW    = nullptr;
    const float* vW    = nullptr;
    for (int i = 0; i < n_in; ++i) {
        if (in_sizes[i] == 8192 * 512)            input = (const float*)d_in[i];
        else if (in_sizes[i] == 512 * 64) {
            if (!kW) kW = (const float*)d_in[i]; else vW = (const float*)d_in[i];
        } else                                    adj = (const int*)d_in[i];
    }
    float* out = (float*)d_out;

    char* ws = (char*)d_ws;
    bf16_t*       khs_hi = (bf16_t*)(ws);                           // 1 MB
    bf16_t*       khs_lo = (bf16_t*)(ws + (1u << 20));              // 1 MB
    bf16_t*       khsF   = (bf16_t*)(ws + (2u << 20));              // 1 MB
    bf16_t*       vhF    = (bf16_t*)(ws + (3u << 20));              // 1 MB
    unsigned int* bits   = (unsigned int*)(ws + (4u << 20));        // 8 MB
    bf16_t*       inputH = (bf16_t*)(ws + (12u << 20));             // 8 MB
    bf16_t*       inputL = (bf16_t*)(ws + (20u << 20));             // 8 MB
    bf16_t*       wimgH  = (bf16_t*)(ws + (28u << 20));             // 128 KB
    bf16_t*       wimgL  = (bf16_t*)(ws + (28u << 20) + (128u << 10)); // 128 KB

    prep1_kernel<<<2080, 256, 0, stream>>>(input, kW, vW, inputH, inputL, wimgH, wimgL);
    projpack_kernel<<<1536, 512, 0, stream>>>(inputH, inputL, wimgH, wimgL, adj,
                                              khs_hi, khs_lo, khsF, vhF, bits);
    attn_kernel<<<512, 512, 0, stream>>>(bits, khs_hi, khs_lo, khsF, vhF, out);
}

// Round 8
// 424.375 us; speedup vs baseline: 1.1035x; 1.1035x over previous
//
#include <hip/hip_runtime.h>
#include <math.h>

typedef __bf16 bf16_t;
typedef __bf16 bf16x8 __attribute__((ext_vector_type(8)));
typedef float f32x4 __attribute__((ext_vector_type(4)));
typedef int   i32x4 __attribute__((ext_vector_type(4)));

#define NN 8192
#define L2E 1.44269504088896340736f
#define SMAX 45.0f                    // fixed softmax max: s in [-75,+15] after shift, all normal fp32/bf16
#define KSCALE 0.35355339059327373f   // 1/sqrt(8); applied to khs on both sides => kh·kh/8

// ---------------------------------------------------------------------------
// Kernel P1: input/weight conversion only (fast, ~6 us).
//  blocks [0,2048)    : input f32 [8192][512] -> inputH/inputL bf16 hi/lo
//  blocks [2048,2080) : kW,vW -> wimgH/wimgL in B-fragment order
// ---------------------------------------------------------------------------
__global__ __launch_bounds__(256) void prep1_kernel(
    const float* __restrict__ input,
    const float* __restrict__ kW,
    const float* __restrict__ vW,
    bf16_t* __restrict__ inputH,
    bf16_t* __restrict__ inputL,
    bf16_t* __restrict__ wimgH,
    bf16_t* __restrict__ wimgL)
{
    const int b = blockIdx.x;
    if (b < 2048) {
        const size_t idx = ((size_t)b * 256 + threadIdx.x) * 8;
        f32x4 a0 = *(const f32x4*)&input[idx];
        f32x4 a1 = *(const f32x4*)&input[idx + 4];
        bf16x8 h8, l8;
        #pragma unroll
        for (int j = 0; j < 4; ++j) {
            bf16_t h0 = (bf16_t)a0[j], h1 = (bf16_t)a1[j];
            h8[j]     = h0;  l8[j]     = (bf16_t)(a0[j] - (float)h0);
            h8[4 + j] = h1;  l8[4 + j] = (bf16_t)(a1[j] - (float)h1);
        }
        *(bf16x8*)&inputH[idx] = h8;
        *(bf16x8*)&inputL[idx] = l8;
    } else {
        const int gid  = (b - 2048) * 256 + threadIdx.x;   // [0, 8192)
        const int proj = gid >> 12;
        const int r    = gid & 4095;
        const int frag = r >> 6;            // kc*4 + nb
        const int lane = r & 63;
        const int kc   = frag >> 2;
        const int nb   = frag & 3;
        const int quad = lane >> 4;
        const int l15  = lane & 15;
        const float* W = proj ? vW : kW;
        bf16x8 h8, l8;
        #pragma unroll
        for (int j = 0; j < 8; ++j) {
            float w  = W[(size_t)(kc * 32 + quad * 8 + j) * 64 + nb * 16 + l15];
            bf16_t h = (bf16_t)w;
            h8[j] = h;
            l8[j] = (bf16_t)(w - (float)h);
        }
        ((bf16x8*)wimgH)[gid] = h8;
        ((bf16x8*)wimgL)[gid] = l8;
    }
}

// ---------------------------------------------------------------------------
// Kernel 1: projections, no LDS / no sync / no staging (verified R2/R5).
// grid 512 row-tiles x 512 threads; wave w: proj = w>>2 (0=K,1=V), nb = w&3.
// Emits row-major khs_hi/lo (Q fragments) and K/V MFMA-fragment images
// khsF/vhF (attn 1KB-burst operands, R5-verified).
// ---------------------------------------------------------------------------
__global__ __launch_bounds__(512) void proj_kernel(
    const bf16_t* __restrict__ inputH,
    const bf16_t* __restrict__ inputL,
    const bf16_t* __restrict__ wimgH,
    const bf16_t* __restrict__ wimgL,
    bf16_t* __restrict__ khs_hi,
    bf16_t* __restrict__ khs_lo,
    bf16_t* __restrict__ khsF,
    bf16_t* __restrict__ vhF)
{
    const int tid   = threadIdx.x;
    const int w     = tid >> 6;
    const int lane  = tid & 63;
    const int proj  = w >> 2;
    const int nb    = w & 3;
    const int l15   = lane & 15;
    const int quad  = lane >> 4;
    const int rbase = blockIdx.x * 16;

    const bf16x8* ah_p = (const bf16x8*)&inputH[(size_t)(rbase + l15) * 512 + quad * 8];
    const bf16x8* al_p = (const bf16x8*)&inputL[(size_t)(rbase + l15) * 512 + quad * 8];
    const bf16x8* bh_p = (const bf16x8*)wimgH + ((size_t)proj * 64 + nb) * 64 + lane;
    const bf16x8* bl_p = (const bf16x8*)wimgL + ((size_t)proj * 64 + nb) * 64 + lane;

    f32x4 acc = {};
    #pragma unroll
    for (int kc = 0; kc < 16; ++kc) {
        bf16x8 ah = ah_p[kc * 4];
        bf16x8 al = al_p[kc * 4];
        bf16x8 bh = bh_p[(size_t)kc * 256];
        bf16x8 bl = bl_p[(size_t)kc * 256];
        acc = __builtin_amdgcn_mfma_f32_16x16x32_bf16(ah, bh, acc, 0, 0, 0);
        acc = __builtin_amdgcn_mfma_f32_16x16x32_bf16(al, bh, acc, 0, 0, 0);
        acc = __builtin_amdgcn_mfma_f32_16x16x32_bf16(ah, bl, acc, 0, 0, 0);
    }

    const int dcol = nb * 16 + l15;
    if (proj == 0) {
        // K: row-major hi/lo (Q fragments) + fragment image (attn B-operand, hi)
        const int kcF = nb >> 1;                                   // k>>5
        const int lf  = (quad * 4) + ((((nb << 1) + (l15 >> 3)) & 3) << 4);
        const int jF  = l15 & 7;                                   // k&7
        bf16_t* kf = &khsF[((size_t)(blockIdx.x * 2 + kcF) * 64 + lf) * 8 + jF];
        #pragma unroll
        for (int r = 0; r < 4; ++r) {
            float v  = acc[r] * KSCALE;
            bf16_t h = (bf16_t)v;
            khs_hi[(size_t)(rbase + quad * 4 + r) * 64 + dcol] = h;
            khs_lo[(size_t)(rbase + quad * 4 + r) * 64 + dcol] = (bf16_t)(v - (float)h);
            kf[r * 8] = h;                      // lane_f advances 1 per key => +8 elems
        }
    } else {
        // V: fragment image only. j = key&7 = (quad&1)*4 + r -> one uint2 store.
        const int kt = blockIdx.x >> 1;                            // key>>5
        const int lf = l15 + ((((blockIdx.x << 1) + (quad >> 1)) & 3) << 4);
        union { bf16_t b[4]; uint2 u; } pk;
        #pragma unroll
        for (int r = 0; r < 4; ++r) pk.b[r] = (bf16_t)acc[r];
        *(uint2*)&vhF[((size_t)(kt * 4 + nb) * 64 + lf) * 8 + (quad & 1) * 4] = pk.u;
    }
}

// ---------------------------------------------------------------------------
// Kernel 2: fixed-max flash attention with IN-KERNEL adj streaming.
// grid 512 row-blocks x 512 threads (8 waves); wave w owns 1024 cols (32x32).
// The separate pack kernel (48us of serial HBM streaming) is deleted: each
// wave streams its own 16 rows x 1024 cols of adj in 4 chunks of 256 cols
// (per row: 64 lanes x dwordx4 = 1KB contiguous burst), packs to bit-words
// (4-bit nibble -> 3 xor-shuffles -> u32, bit j == col W*32+j, identical to
// the old bits[] layout) into a per-wave LDS region. Chunk 0 staged in a
// short prologue; chunk c+1's rows (2/iter) load at iter TOP (before K/V, so
// in-order vmcnt completion makes the end-of-iter pack stall-free) and are
// packed/written at iter end -> the 268MB adj stream hides under compute.
// No __syncthreads (wave-private region); LDS overlays the merge buffer.
// K/V stream from fragment images (R5-verified); R6 K-prefetch dropped
// (neutral; reclaims 16 VGPR for staging — keep under the (512,4) 128 cap).
// ---------------------------------------------------------------------------
__global__ __launch_bounds__(512, 4) void attn_kernel(
    const int* __restrict__ adj,            // [8192][8192]
    const bf16_t* __restrict__ khs_hi,
    const bf16_t* __restrict__ khs_lo,
    const bf16_t* __restrict__ khsF,        // fragment image, hi
    const bf16_t* __restrict__ vhF,         // fragment image
    float* __restrict__ out)                // [8192][64]
{
    // 17408 B: per-wave mask words during the loop, merge buffer after.
    __shared__ __align__(16) unsigned int SMEM[4352];

    const int tid   = threadIdx.x;
    const int w     = tid >> 6;
    const int lane  = tid & 63;
    const int l15   = lane & 15;
    const int quad  = lane >> 4;
    const int qbase = blockIdx.x * 16;
    const int colstart = w * 1024;

    unsigned int* maskW = SMEM + w * 544;   // 16 rows x 34 u32 (pad: banks l15*2+t)

    // Q fragments (m=l15, k=quad*8+j), hi + lo — used as B-operand (n=l15).
    const bf16x8 qh0 = *(const bf16x8*)&khs_hi[(size_t)(qbase + l15) * 64 + quad * 8];
    const bf16x8 qh1 = *(const bf16x8*)&khs_hi[(size_t)(qbase + l15) * 64 + 32 + quad * 8];
    const bf16x8 ql0 = *(const bf16x8*)&khs_lo[(size_t)(qbase + l15) * 64 + quad * 8];
    const bf16x8 ql1 = *(const bf16x8*)&khs_lo[(size_t)(qbase + l15) * 64 + 32 + quad * 8];

    bf16x8 ones;
    #pragma unroll
    for (int j = 0; j < 8; ++j) ones[j] = (bf16_t)1.0f;

    f32x4 o0 = {}, o1 = {}, o2 = {}, o3 = {}, o4 = {};

    // fragment streams: contiguous, +256 bf16x8 (4KB) per iter
    const bf16x8* kF = (const bf16x8*)khsF + (size_t)(colstart >> 4) * 128 + lane;
    const bf16x8* vF = (const bf16x8*)vhF  + (size_t)(colstart >> 5) * 256 + lane;

    // bpermute source lanes for the in-register P transpose:
    const int idxA = (l15 + (((2 * quad)    ) & 3) * 16) * 4;
    const int idxB = (l15 + (((2 * quad) | 1) & 3) * 16) * 4;

    // adj staging base: lane L covers cols colstart + c*256 + L*4 + [0..3]
    const int* adjw = adj + (size_t)qbase * NN + colstart + lane * 4;

    // ---- prologue: stage chunk 0 (16 rows, 1KB burst per row per wave) ----
    #pragma unroll 4
    for (int r = 0; r < 16; ++r) {
        i32x4 v = *(const i32x4*)(adjw + (size_t)r * NN);
        int n = (v[0] > 0) | ((v[1] > 0) << 1) | ((v[2] > 0) << 2) | ((v[3] > 0) << 3);
        n |= __shfl_xor(n, 1) << 4;
        n |= __shfl_xor(n, 2) << 8;
        n |= __shfl_xor(n, 4) << 16;
        if ((lane & 7) == 0) maskW[r * 34 + (lane >> 3)] = (unsigned int)n;
    }

    for (int t = 0; t < 32; ++t) {
        // staged adj loads for chunk (t/8)+1, rows 2*(t&7),+1 — issued FIRST
        // (in-order vmcnt: K/V waits imply these are done by the iter-end pack)
        i32x4 sa = {}, sb = {};
        int sr0 = 0, sc = 0;
        if (t < 24) {
            sc  = (t >> 3) + 1;
            sr0 = (t & 7) * 2;
            sa = *(const i32x4*)(adjw + (size_t)sr0 * NN + sc * 256);
            sb = *(const i32x4*)(adjw + (size_t)(sr0 + 1) * NN + sc * 256);
        }

        // K then V fragment loads (consumption order: S-MFMA first, PV last)
        bf16x8 bh00 = kF[t * 256];
        bf16x8 bh01 = kF[t * 256 + 64];
        bf16x8 bh10 = kF[t * 256 + 128];
        bf16x8 bh11 = kF[t * 256 + 192];
        bf16x8 bv0  = vF[t * 256];
        bf16x8 bv1  = vF[t * 256 + 64];
        bf16x8 bv2  = vF[t * 256 + 128];
        bf16x8 bv3  = vF[t * 256 + 192];

        // mask word for this iter from the per-wave LDS region (own row = l15)
        unsigned int mcur = maskW[l15 * 34 + t];

        // S^T: query = lane&15 (col), key = quad*4+reg (row). Swapped operands,
        // bitwise-identical dot products to the Q-major form.
        f32x4 zz = {};
        f32x4 s0 = __builtin_amdgcn_mfma_f32_16x16x32_bf16(bh00, qh0, zz, 0, 0, 0);
        s0 = __builtin_amdgcn_mfma_f32_16x16x32_bf16(bh01, qh1, s0, 0, 0, 0);
        s0 = __builtin_amdgcn_mfma_f32_16x16x32_bf16(bh00, ql0, s0, 0, 0, 0);
        s0 = __builtin_amdgcn_mfma_f32_16x16x32_bf16(bh01, ql1, s0, 0, 0, 0);
        f32x4 s1 = __builtin_amdgcn_mfma_f32_16x16x32_bf16(bh10, qh0, zz, 0, 0, 0);
        s1 = __builtin_amdgcn_mfma_f32_16x16x32_bf16(bh11, qh1, s1, 0, 0, 0);
        s1 = __builtin_amdgcn_mfma_f32_16x16x32_bf16(bh10, ql0, s1, 0, 0, 0);
        s1 = __builtin_amdgcn_mfma_f32_16x16x32_bf16(bh11, ql1, s1, 0, 0, 0);

        // p = maskbit ? exp(s - SMAX) : 0; key for s0[r] = colbase+quad*4+r,
        // for s1[r] = colbase+16+quad*4+r; mask row = qbase+l15 (own row!)
        union { bf16_t b[2]; int u; } k0, k1, k2, k3;
        #pragma unroll
        for (int r = 0; r < 4; ++r) {
            float p0 = ((mcur >> (quad * 4 + r)) & 1u)
                         ? __builtin_amdgcn_exp2f((s0[r] - SMAX) * L2E) : 0.f;
            float p1 = ((mcur >> (16 + quad * 4 + r)) & 1u)
                         ? __builtin_amdgcn_exp2f((s1[r] - SMAX) * L2E) : 0.f;
            if (r < 2) { k0.b[r] = (bf16_t)p0; k2.b[r] = (bf16_t)p1; }
            else       { k1.b[r - 2] = (bf16_t)p0; k3.b[r - 2] = (bf16_t)p1; }
        }

        // in-register transpose: pull bf16 pairs from the source quads
        int a0 = __builtin_amdgcn_ds_bpermute(idxA, k0.u);
        int a1 = __builtin_amdgcn_ds_bpermute(idxA, k1.u);
        int a2 = __builtin_amdgcn_ds_bpermute(idxB, k0.u);
        int a3 = __builtin_amdgcn_ds_bpermute(idxB, k1.u);
        int c0 = __builtin_amdgcn_ds_bpermute(idxA, k2.u);
        int c1 = __builtin_amdgcn_ds_bpermute(idxA, k3.u);
        int c2 = __builtin_amdgcn_ds_bpermute(idxB, k2.u);
        int c3 = __builtin_amdgcn_ds_bpermute(idxB, k3.u);

        union { int u[4]; bf16x8 v; } pa;
        pa.u[0] = quad < 2 ? a0 : c0;
        pa.u[1] = quad < 2 ? a1 : c1;
        pa.u[2] = quad < 2 ? a2 : c2;
        pa.u[3] = quad < 2 ? a3 : c3;

        // unnormalized accumulation: O += P·V, l += P·1  (no rescale — fixed max)
        o0 = __builtin_amdgcn_mfma_f32_16x16x32_bf16(pa.v, bv0, o0, 0, 0, 0);
        o1 = __builtin_amdgcn_mfma_f32_16x16x32_bf16(pa.v, bv1, o1, 0, 0, 0);
        o2 = __builtin_amdgcn_mfma_f32_16x16x32_bf16(pa.v, bv2, o2, 0, 0, 0);
        o3 = __builtin_amdgcn_mfma_f32_16x16x32_bf16(pa.v, bv3, o3, 0, 0, 0);
        o4 = __builtin_amdgcn_mfma_f32_16x16x32_bf16(pa.v, ones, o4, 0, 0, 0);

        // pack + write the staged rows (loads completed long ago; wave-local)
        if (t < 24) {
            int n0 = (sa[0] > 0) | ((sa[1] > 0) << 1) | ((sa[2] > 0) << 2) | ((sa[3] > 0) << 3);
            n0 |= __shfl_xor(n0, 1) << 4;
            n0 |= __shfl_xor(n0, 2) << 8;
            n0 |= __shfl_xor(n0, 4) << 16;
            int n1 = (sb[0] > 0) | ((sb[1] > 0) << 1) | ((sb[2] > 0) << 2) | ((sb[3] > 0) << 3);
            n1 |= __shfl_xor(n1, 1) << 4;
            n1 |= __shfl_xor(n1, 2) << 8;
            n1 |= __shfl_xor(n1, 4) << 16;
            if ((lane & 7) == 0) {
                maskW[sr0 * 34 + sc * 8 + (lane >> 3)]       = (unsigned int)n0;
                maskW[(sr0 + 1) * 34 + sc * 8 + (lane >> 3)] = (unsigned int)n1;
            }
        }
    }

    // ---- sum-tree merge of the 8 waves (overlays SMEM; all mask reads done
    // before the first barrier, so the overlay is race-free) ----
    float* M = (float*)SMEM;   // [4][16][68] floats = 17408 B
    #pragma unroll
    for (int s = 4; s >= 1; s >>= 1) {
        __syncthreads();
        if (w >= s && w < 2 * s) {
            float* base = M + (w - s) * 16 * 68;
            #pragma unroll
            for (int r = 0; r < 4; ++r) {
                const int row = quad * 4 + r;
                base[row * 68 + l15]      = o0[r];
                base[row * 68 + 16 + l15] = o1[r];
                base[row * 68 + 32 + l15] = o2[r];
                base[row * 68 + 48 + l15] = o3[r];
                if (l15 == 0) base[row * 68 + 64] = o4[r];
            }
        }
        __syncthreads();
        if (w < s) {
            float* base = M + w * 16 * 68;
            #pragma unroll
            for (int r = 0; r < 4; ++r) {
                const int row = quad * 4 + r;
                o0[r] += base[row * 68 + l15];
                o1[r] += base[row * 68 + 16 + l15];
                o2[r] += base[row * 68 + 32 + l15];
                o3[r] += base[row * 68 + 48 + l15];
                o4[r] += base[row * 68 + 64];   // all 16 lanes same value invariant
            }
        }
    }

    // ---- fused normalize + ELU + store (block owns the whole row) ----
    if (w == 0) {
        #pragma unroll
        for (int r = 0; r < 4; ++r) {
            const size_t row = (size_t)qbase + quad * 4 + r;
            float l   = o4[r];
            float inv = 1.0f / (l > 0.f ? l : 1.0f);
            float v0 = o0[r] * inv, v1 = o1[r] * inv, v2 = o2[r] * inv, v3 = o3[r] * inv;
            out[row * 64 + l15]      = v0 > 0.f ? v0 : expm1f(v0);
            out[row * 64 + 16 + l15] = v1 > 0.f ? v1 : expm1f(v1);
            out[row * 64 + 32 + l15] = v2 > 0.f ? v2 : expm1f(v2);
            out[row * 64 + 48 + l15] = v3 > 0.f ? v3 : expm1f(v3);
        }
    }
}

// ---------------------------------------------------------------------------
extern "C" void kernel_launch(void* const* d_in, const int* in_sizes, int n_in,
                              void* d_out, int out_size, void* d_ws, size_t ws_size,
                              hipStream_t stream) {
    const float* input = nullptr;
    const int*   adj   = nullptr;
    const float* kW    = nullptr;
    const float* vW    = nullptr;
    for (int i = 0; i < n_in; ++i) {
        if (in_sizes[i] == 8192 * 512)            input = (const float*)d_in[i];
        else if (in_sizes[i] == 512 * 64) {
            if (!kW) kW = (const float*)d_in[i]; else vW = (const float*)d_in[i];
        } else                                    adj = (const int*)d_in[i];
    }
    float* out = (float*)d_out;

    char* ws = (char*)d_ws;
    bf16_t*       khs_hi = (bf16_t*)(ws);                           // 1 MB
    bf16_t*       khs_lo = (bf16_t*)(ws + (1u << 20));              // 1 MB
    bf16_t*       khsF   = (bf16_t*)(ws + (2u << 20));              // 1 MB
    bf16_t*       vhF    = (bf16_t*)(ws + (3u << 20));              // 1 MB
    bf16_t*       inputH = (bf16_t*)(ws + (12u << 20));             // 8 MB
    bf16_t*       inputL = (bf16_t*)(ws + (20u << 20));             // 8 MB
    bf16_t*       wimgH  = (bf16_t*)(ws + (28u << 20));             // 128 KB
    bf16_t*       wimgL  = (bf16_t*)(ws + (28u << 20) + (128u << 10)); // 128 KB

    prep1_kernel<<<2080, 256, 0, stream>>>(input, kW, vW, inputH, inputL, wimgH, wimgL);
    proj_kernel<<<512, 512, 0, stream>>>(inputH, inputL, wimgH, wimgL,
                                         khs_hi, khs_lo, khsF, vhF);
    attn_kernel<<<512, 512, 0, stream>>>(adj, khs_hi, khs_lo, khsF, vhF, out);
}